// Round 5
// baseline (191.031 us; speedup 1.0000x reference)
//
#include <hip/hip_runtime.h>
#include <hip/hip_cooperative_groups.h>
#include <math.h>

namespace cg = cooperative_groups;

#define T_LEN 2048
#define LN_EPS 1e-5f

using u16x8  = __attribute__((ext_vector_type(8))) unsigned short;
using bf16x8 = __attribute__((ext_vector_type(8))) short;
using f32x4  = __attribute__((ext_vector_type(4))) float;

__device__ __forceinline__ unsigned short f2bf(float f) {
    unsigned int u = __float_as_uint(f);
    u += 0x7FFFu + ((u >> 16) & 1u);
    return (unsigned short)(u >> 16);
}
__device__ __forceinline__ float bf2f(unsigned short u) {
    return __uint_as_float(((unsigned int)u) << 16);
}
__device__ __forceinline__ void gload16(const void* g, void* l) {
    __builtin_amdgcn_global_load_lds(
        (const __attribute__((address_space(1))) unsigned int*)g,
        (__attribute__((address_space(3))) unsigned int*)l, 16, 0, 0);
}

// Shared 8-wave LN epilogue: acc[2][2] covers 32 rows x (wave-owned 32 cols).
template<bool RES_F32, bool OUT_F32>
__device__ __forceinline__ void ln_epi8(
    f32x4 (&acc)[2][2], float* part,
    const float* __restrict__ bias, const void* __restrict__ resv,
    const float* __restrict__ gamma, const float* __restrict__ beta,
    void* __restrict__ outv, int m0, int lane, int wid)
{
    float v[2][2][4];
    float s[2][4], sq[2][4];
    #pragma unroll
    for (int m = 0; m < 2; ++m)
        #pragma unroll
        for (int j = 0; j < 4; ++j) { s[m][j] = 0.f; sq[m][j] = 0.f; }

    #pragma unroll
    for (int n = 0; n < 2; ++n) {
        const int c = wid * 32 + n * 16 + (lane & 15);
        const float bv = bias[c];
        #pragma unroll
        for (int m = 0; m < 2; ++m) {
            const int rb = m * 16 + ((lane >> 4) << 2);
            #pragma unroll
            for (int j = 0; j < 4; ++j) {
                float x = acc[m][n][j] + bv;
                if (RES_F32)
                    x += ((const float*)resv)[(size_t)(m0 + rb + j) * 256 + c];
                else
                    x += bf2f(((const unsigned short*)resv)[(size_t)(m0 + rb + j) * 256 + c]);
                v[m][n][j] = x; s[m][j] += x; sq[m][j] += x * x;
            }
        }
    }
    #pragma unroll
    for (int m = 0; m < 2; ++m)
        #pragma unroll
        for (int j = 0; j < 4; ++j) {
            #pragma unroll
            for (int msk = 1; msk <= 8; msk <<= 1) {
                s[m][j]  += __shfl_xor(s[m][j], msk);
                sq[m][j] += __shfl_xor(sq[m][j], msk);
            }
            if ((lane & 15) == 0) {
                const int r = m * 16 + ((lane >> 4) << 2) + j;
                part[(wid * 32 + r) * 2 + 0] = s[m][j];
                part[(wid * 32 + r) * 2 + 1] = sq[m][j];
            }
        }
    __syncthreads();
    #pragma unroll
    for (int m = 0; m < 2; ++m) {
        const int rb = m * 16 + ((lane >> 4) << 2);
        #pragma unroll
        for (int j = 0; j < 4; ++j) {
            const int r = rb + j;
            float S = 0.f, SQ = 0.f;
            #pragma unroll
            for (int w = 0; w < 8; ++w) {
                S  += part[(w * 32 + r) * 2 + 0];
                SQ += part[(w * 32 + r) * 2 + 1];
            }
            const float mean = S * (1.f / 256.f);
            const float var  = SQ * (1.f / 256.f) - mean * mean;
            const float rstd = rsqrtf(var + LN_EPS);
            #pragma unroll
            for (int n = 0; n < 2; ++n) {
                const int c = wid * 32 + n * 16 + (lane & 15);
                const float o = (v[m][n][j] - mean) * rstd * gamma[c] + beta[c];
                if (OUT_F32)
                    ((float*)outv)[(size_t)(m0 + r) * 256 + c] = o;
                else
                    ((unsigned short*)outv)[(size_t)(m0 + r) * 256 + c] = f2bf(o);
            }
        }
    }
}

// ---------------------------------------------------------------------------
// One cooperative kernel: convert | QKV | attn+proj+LN1 | FFN1 | FFN2+LN2.
// 256 blocks x 512 threads (1 block/CU), grid.sync() between phases.
// ---------------------------------------------------------------------------
__global__ __launch_bounds__(512, 2) void mega(
    const float* __restrict__ features, const float* __restrict__ w_qkv,
    const float* __restrict__ b_qkv, const float* __restrict__ w_out,
    const float* __restrict__ b_out, const float* __restrict__ w1,
    const float* __restrict__ b1, const float* __restrict__ w2,
    const float* __restrict__ b2, const float* __restrict__ g1,
    const float* __restrict__ be1, const float* __restrict__ g2,
    const float* __restrict__ be2, unsigned short* __restrict__ ws,
    float* __restrict__ out)
{
    __shared__ __align__(16) char sm[83968];
    float* part = (float*)(sm + 81920);

    unsigned short* featbf = ws;
    unsigned short* wqkvbf = ws + 2097152;
    unsigned short* woutbf = ws + 2293760;
    unsigned short* w1bf   = ws + 2359296;
    unsigned short* w2bf   = ws + 2490368;
    unsigned short* qkvbf  = ws + 2621440;   // [8192][768]
    unsigned short* xbf    = ws + 8912896;   // [8192][256]
    unsigned short* hidbf  = ws + 11010048;  // [8192][512]

    const int tid = threadIdx.x, lane = tid & 63, wid = tid >> 6;
    const int bid = blockIdx.x;
    cg::grid_group gg = cg::this_grid();

    // ================= phase 0: fp32 -> bf16 =================
    for (int s = bid * 512 + tid; s < 327680; s += 131072) {
        const float* src; unsigned short* dst;
        if (s < 262144) { src = features + (size_t)s * 8; dst = featbf + (size_t)s * 8; }
        else {
            const int w8 = s - 262144;
            if (w8 < 24576)      { src = w_qkv + (size_t)w8 * 8;           dst = wqkvbf + (size_t)w8 * 8; }
            else if (w8 < 32768) { src = w_out + (size_t)(w8 - 24576) * 8; dst = woutbf + (size_t)(w8 - 24576) * 8; }
            else if (w8 < 49152) { src = w1 + (size_t)(w8 - 32768) * 8;    dst = w1bf + (size_t)(w8 - 32768) * 8; }
            else                 { src = w2 + (size_t)(w8 - 49152) * 8;    dst = w2bf + (size_t)(w8 - 49152) * 8; }
        }
        const float4 a = *(const float4*)src;
        const float4 b4 = *(const float4*)(src + 4);
        u16x8 p;
        p[0] = f2bf(a.x);  p[1] = f2bf(a.y);  p[2] = f2bf(a.z);  p[3] = f2bf(a.w);
        p[4] = f2bf(b4.x); p[5] = f2bf(b4.y); p[6] = f2bf(b4.z); p[7] = f2bf(b4.w);
        *(u16x8*)dst = p;
    }
    gg.sync();

    // ================= phase 1: QKV GEMM (128x192, BK=128) =================
    {
        char* As = sm;                 // [128][128] bf16
        char* Bs = sm + 32768;         // [192][128] bf16
        const int m0 = (bid >> 2) * 128, n0 = (bid & 3) * 192;
        const int wr = wid >> 2, wcl = wid & 3;
        f32x4 acc[4][3];
        #pragma unroll
        for (int m = 0; m < 4; ++m)
            #pragma unroll
            for (int n = 0; n < 3; ++n) acc[m][n] = (f32x4)(0.f);

        for (int k0 = 0; k0 < 256; k0 += 128) {
            #pragma unroll
            for (int j = 0; j < 4; ++j) {
                const int i = j * 512 + tid, row = i >> 4, k8 = (i & 15) ^ (row & 7);
                gload16(featbf + (size_t)(m0 + row) * 256 + k0 + k8 * 8, As + i * 16);
            }
            #pragma unroll
            for (int j = 0; j < 6; ++j) {
                const int i = j * 512 + tid, row = i >> 4, k8 = (i & 15) ^ (row & 7);
                gload16(wqkvbf + (size_t)(n0 + row) * 256 + k0 + k8 * 8, Bs + i * 16);
            }
            __syncthreads();
            #pragma unroll
            for (int ks = 0; ks < 4; ++ks) {
                bf16x8 af[4], bfr[3];
                #pragma unroll
                for (int m = 0; m < 4; ++m) {
                    const int r = wr * 64 + m * 16 + (lane & 15);
                    af[m] = *(const bf16x8*)(As + r * 256 + ((ks * 4 + (lane >> 4)) ^ (r & 7)) * 16);
                }
                #pragma unroll
                for (int n = 0; n < 3; ++n) {
                    const int r = wcl * 48 + n * 16 + (lane & 15);
                    bfr[n] = *(const bf16x8*)(Bs + r * 256 + ((ks * 4 + (lane >> 4)) ^ (r & 7)) * 16);
                }
                #pragma unroll
                for (int m = 0; m < 4; ++m)
                    #pragma unroll
                    for (int n = 0; n < 3; ++n)
                        acc[m][n] = __builtin_amdgcn_mfma_f32_16x16x32_bf16(
                            af[m], bfr[n], acc[m][n], 0, 0, 0);
            }
            __syncthreads();
        }
        #pragma unroll
        for (int n = 0; n < 3; ++n) {
            const int c = n0 + wcl * 48 + n * 16 + (lane & 15);
            const float bv = b_qkv[c];
            #pragma unroll
            for (int m = 0; m < 4; ++m) {
                const int rb = m0 + wr * 64 + m * 16 + ((lane >> 4) << 2);
                #pragma unroll
                for (int j = 0; j < 4; ++j)
                    qkvbf[(size_t)(rb + j) * 768 + c] = f2bf(acc[m][n][j] + bv);
            }
        }
    }
    gg.sync();

    // ============ phase 2: attention + out-proj + res + LN1 ============
    {
        char* As = sm;                 // [32][256] bf16 (A-tile from attention)
        char* Bs = sm + 16384;         // [256][128] bf16
        const int m0 = bid * 32;
        const int b = m0 >> 11, t0 = m0 & 2047;

        if (tid < 256) {
            const int h = tid & 7, tl = tid >> 3;
            const int t = t0 + tl;
            const unsigned short* base = qkvbf + (size_t)b * T_LEN * 768;

            float q[32];
            const unsigned short* qp = base + (size_t)t * 768 + h * 32;
            #pragma unroll
            for (int jj = 0; jj < 4; ++jj) {
                u16x8 u = *(const u16x8*)(qp + jj * 8);
                #pragma unroll
                for (int e = 0; e < 8; ++e) q[jj * 8 + e] = bf2f(u[e]);
            }
            const unsigned short* kbase = base + 256 + h * 32;
            const unsigned short* vbase = base + 512 + h * 32;

            float sc[9], mx = -1e30f;
            #pragma unroll
            for (int j = 0; j < 9; ++j) {
                const int kr0 = t - 4 + j;
                const int krm = min(max(kr0, 0), T_LEN - 1);
                const unsigned short* kr = kbase + (size_t)krm * 768;
                float d = 0.f;
                #pragma unroll
                for (int jj = 0; jj < 4; ++jj) {
                    u16x8 u = *(const u16x8*)(kr + jj * 8);
                    #pragma unroll
                    for (int e = 0; e < 8; ++e) d += q[jj * 8 + e] * bf2f(u[e]);
                }
                sc[j] = (kr0 == krm) ? d * 0.17677669529663687f : -1e30f;
                mx = fmaxf(mx, sc[j]);
            }
            float sum = 0.f;
            #pragma unroll
            for (int j = 0; j < 9; ++j) { sc[j] = expf(sc[j] - mx); sum += sc[j]; }
            const float inv = 1.f / sum;

            float ov[32] = {};
            #pragma unroll
            for (int j = 0; j < 9; ++j) {
                const float p = sc[j] * inv;
                const int krm = min(max(t - 4 + j, 0), T_LEN - 1);
                const unsigned short* vr = vbase + (size_t)krm * 768;
                #pragma unroll
                for (int jj = 0; jj < 4; ++jj) {
                    u16x8 u = *(const u16x8*)(vr + jj * 8);
                    #pragma unroll
                    for (int e = 0; e < 8; ++e) ov[jj * 8 + e] += p * bf2f(u[e]);
                }
            }
            #pragma unroll
            for (int jj = 0; jj < 4; ++jj) {
                u16x8 p8;
                #pragma unroll
                for (int e = 0; e < 8; ++e) p8[e] = f2bf(ov[jj * 8 + e]);
                const int off = tl * 512 + ((h * 4 + jj) ^ (tl & 7)) * 16;
                *(u16x8*)(As + off) = p8;
            }
        }
        __syncthreads();

        f32x4 acc[2][2];
        #pragma unroll
        for (int m = 0; m < 2; ++m)
            #pragma unroll
            for (int n = 0; n < 2; ++n) acc[m][n] = (f32x4)(0.f);

        for (int k0 = 0; k0 < 256; k0 += 128) {
            #pragma unroll
            for (int j = 0; j < 8; ++j) {
                const int i = j * 512 + tid, row = i >> 4, k8 = (i & 15) ^ (row & 7);
                gload16(woutbf + (size_t)row * 256 + k0 + k8 * 8, Bs + i * 16);
            }
            __syncthreads();
            #pragma unroll
            for (int ks = 0; ks < 4; ++ks) {
                bf16x8 af[2], bfr[2];
                #pragma unroll
                for (int m = 0; m < 2; ++m) {
                    const int r = m * 16 + (lane & 15);
                    af[m] = *(const bf16x8*)(As + r * 512
                            + ((k0 >> 3) + ((ks * 4 + (lane >> 4)) ^ (r & 7))) * 16);
                }
                #pragma unroll
                for (int n = 0; n < 2; ++n) {
                    const int r = wid * 32 + n * 16 + (lane & 15);
                    bfr[n] = *(const bf16x8*)(Bs + r * 256 + ((ks * 4 + (lane >> 4)) ^ (r & 7)) * 16);
                }
                #pragma unroll
                for (int m = 0; m < 2; ++m)
                    #pragma unroll
                    for (int n = 0; n < 2; ++n)
                        acc[m][n] = __builtin_amdgcn_mfma_f32_16x16x32_bf16(
                            af[m], bfr[n], acc[m][n], 0, 0, 0);
            }
            __syncthreads();
        }
        ln_epi8<true, false>(acc, part, b_out, features, g1, be1, xbf, m0, lane, wid);
    }
    gg.sync();

    // ================= phase 3: FFN1 (128x128, relu) =================
    {
        char* As = sm;                 // [128][128]
        char* Bs = sm + 32768;         // [128][128]
        const int m0 = (bid >> 2) * 128, n0 = (bid & 3) * 128;
        const int wr = wid >> 2, wc = wid & 3;
        f32x4 acc[4][2];
        #pragma unroll
        for (int m = 0; m < 4; ++m)
            #pragma unroll
            for (int n = 0; n < 2; ++n) acc[m][n] = (f32x4)(0.f);

        for (int k0 = 0; k0 < 256; k0 += 128) {
            #pragma unroll
            for (int j = 0; j < 4; ++j) {
                const int i = j * 512 + tid, row = i >> 4, k8 = (i & 15) ^ (row & 7);
                gload16(xbf + (size_t)(m0 + row) * 256 + k0 + k8 * 8, As + i * 16);
                gload16(w1bf + (size_t)(n0 + row) * 256 + k0 + k8 * 8, Bs + i * 16);
            }
            __syncthreads();
            #pragma unroll
            for (int ks = 0; ks < 4; ++ks) {
                bf16x8 af[4], bfr[2];
                #pragma unroll
                for (int m = 0; m < 4; ++m) {
                    const int r = wr * 64 + m * 16 + (lane & 15);
                    af[m] = *(const bf16x8*)(As + r * 256 + ((ks * 4 + (lane >> 4)) ^ (r & 7)) * 16);
                }
                #pragma unroll
                for (int n = 0; n < 2; ++n) {
                    const int r = wc * 32 + n * 16 + (lane & 15);
                    bfr[n] = *(const bf16x8*)(Bs + r * 256 + ((ks * 4 + (lane >> 4)) ^ (r & 7)) * 16);
                }
                #pragma unroll
                for (int m = 0; m < 4; ++m)
                    #pragma unroll
                    for (int n = 0; n < 2; ++n)
                        acc[m][n] = __builtin_amdgcn_mfma_f32_16x16x32_bf16(
                            af[m], bfr[n], acc[m][n], 0, 0, 0);
            }
            __syncthreads();
        }
        #pragma unroll
        for (int n = 0; n < 2; ++n) {
            const int c = n0 + wc * 32 + n * 16 + (lane & 15);
            const float bv = b1[c];
            #pragma unroll
            for (int m = 0; m < 4; ++m) {
                const int rb = m0 + wr * 64 + m * 16 + ((lane >> 4) << 2);
                #pragma unroll
                for (int j = 0; j < 4; ++j)
                    hidbf[(size_t)(rb + j) * 512 + c] = f2bf(fmaxf(acc[m][n][j] + bv, 0.f));
            }
        }
    }
    gg.sync();

    // ============ phase 4: FFN2 + res + LN2 -> out (f32) ============
    {
        char* As = sm;                 // [32][128]
        char* Bs = sm + 8192;          // [256][128]
        const int m0 = bid * 32;
        f32x4 acc[2][2];
        #pragma unroll
        for (int m = 0; m < 2; ++m)
            #pragma unroll
            for (int n = 0; n < 2; ++n) acc[m][n] = (f32x4)(0.f);

        for (int k0 = 0; k0 < 512; k0 += 128) {
            #pragma unroll
            for (int j = 0; j < 9; ++j) {
                const int i = j * 512 + tid;
                if (i < 512) {
                    const int row = i >> 4, k8 = (i & 15) ^ (row & 7);
                    gload16(hidbf + (size_t)(m0 + row) * 512 + k0 + k8 * 8, As + i * 16);
                } else {
                    const int ii = i - 512, row = ii >> 4, k8 = (ii & 15) ^ (row & 7);
                    gload16(w2bf + (size_t)row * 512 + k0 + k8 * 8, Bs + ii * 16);
                }
            }
            __syncthreads();
            #pragma unroll
            for (int ks = 0; ks < 4; ++ks) {
                bf16x8 af[2], bfr[2];
                #pragma unroll
                for (int m = 0; m < 2; ++m) {
                    const int r = m * 16 + (lane & 15);
                    af[m] = *(const bf16x8*)(As + r * 256 + ((ks * 4 + (lane >> 4)) ^ (r & 7)) * 16);
                }
                #pragma unroll
                for (int n = 0; n < 2; ++n) {
                    const int r = wid * 32 + n * 16 + (lane & 15);
                    bfr[n] = *(const bf16x8*)(Bs + r * 256 + ((ks * 4 + (lane >> 4)) ^ (r & 7)) * 16);
                }
                #pragma unroll
                for (int m = 0; m < 2; ++m)
                    #pragma unroll
                    for (int n = 0; n < 2; ++n)
                        acc[m][n] = __builtin_amdgcn_mfma_f32_16x16x32_bf16(
                            af[m], bfr[n], acc[m][n], 0, 0, 0);
            }
            __syncthreads();
        }
        ln_epi8<false, true>(acc, part, b2, xbf, g2, be2, out, m0, lane, wid);
    }
}

// ---------------------------------------------------------------------------
extern "C" void kernel_launch(void* const* d_in, const int* in_sizes, int n_in,
                              void* d_out, int out_size, void* d_ws, size_t ws_size,
                              hipStream_t stream) {
    const float* features = (const float*)d_in[0];
    const float* w_qkv    = (const float*)d_in[1];
    const float* b_qkv    = (const float*)d_in[2];
    const float* w_out    = (const float*)d_in[3];
    const float* b_out    = (const float*)d_in[4];
    const float* w1       = (const float*)d_in[5];
    const float* b1       = (const float*)d_in[6];
    const float* w2       = (const float*)d_in[7];
    const float* b2       = (const float*)d_in[8];
    const float* g1       = (const float*)d_in[9];
    const float* be1      = (const float*)d_in[10];
    const float* g2       = (const float*)d_in[11];
    const float* be2      = (const float*)d_in[12];
    // d_in[13] (mask) structurally determined by WIN=9 -> not read.

    unsigned short* wsu = (unsigned short*)d_ws;
    float* outf = (float*)d_out;

    void* args[] = {
        (void*)&features, (void*)&w_qkv, (void*)&b_qkv, (void*)&w_out,
        (void*)&b_out, (void*)&w1, (void*)&b1, (void*)&w2, (void*)&b2,
        (void*)&g1, (void*)&be1, (void*)&g2, (void*)&be2,
        (void*)&wsu, (void*)&outf};
    hipLaunchCooperativeKernel((void*)mega, dim3(256), dim3(512), args, 0, stream);
}

// Round 6
// 49.720 us; speedup vs baseline: 3.8421x; 3.8421x over previous
//
#include <hip/hip_runtime.h>
#include <math.h>

#define T_LEN 2048
#define LN_EPS 1e-5f
#define M_ROWS 8192

using u16x8  = __attribute__((ext_vector_type(8))) unsigned short;
using bf16x8 = __attribute__((ext_vector_type(8))) short;
using f32x4  = __attribute__((ext_vector_type(4))) float;

__device__ __forceinline__ unsigned short f2bf(float f) {
    unsigned int u = __float_as_uint(f);
    u += 0x7FFFu + ((u >> 16) & 1u);
    return (unsigned short)(u >> 16);
}
__device__ __forceinline__ float bf2f(unsigned short u) {
    return __uint_as_float(((unsigned int)u) << 16);
}
__device__ __forceinline__ void gload16(const void* g, void* l) {
    __builtin_amdgcn_global_load_lds(
        (const __attribute__((address_space(1))) unsigned int*)g,
        (__attribute__((address_space(3))) unsigned int*)l, 16, 0, 0);
}

// ---------------------------------------------------------------------------
// fp32 -> bf16 of {features, w_qkv, w_out, w1, w2}.
// ---------------------------------------------------------------------------
__global__ __launch_bounds__(256) void to_bf16_multi(
    const float* __restrict__ s0, const float* __restrict__ s1,
    const float* __restrict__ s2, const float* __restrict__ s3,
    const float* __restrict__ s4, unsigned short* __restrict__ dst)
{
    const long i8 = ((long)blockIdx.x * 256 + threadIdx.x) * 8;
    const float* src; long off;
    if (i8 < 2097152)      { src = s0; off = 0; }
    else if (i8 < 2293760) { src = s1; off = 2097152; }
    else if (i8 < 2359296) { src = s2; off = 2293760; }
    else if (i8 < 2490368) { src = s3; off = 2359296; }
    else                   { src = s4; off = 2490368; }
    const float4 a = *(const float4*)(src + (i8 - off));
    const float4 b = *(const float4*)(src + (i8 - off) + 4);
    u16x8 p;
    p[0] = f2bf(a.x); p[1] = f2bf(a.y); p[2] = f2bf(a.z); p[3] = f2bf(a.w);
    p[4] = f2bf(b.x); p[5] = f2bf(b.y); p[6] = f2bf(b.z); p[7] = f2bf(b.w);
    *(u16x8*)(dst + i8) = p;
}

// ---------------------------------------------------------------------------
// QKV GEMM: C[8192,768] = A[8192,256] @ W[768,256]^T + bias. bf16.
// 128x192 tile, 512 threads (8 waves, 2x4), grid 64x4 = 256 (tail-free).
// ---------------------------------------------------------------------------
__global__ __launch_bounds__(512) void qkv_gemm(
    const unsigned short* __restrict__ A, const unsigned short* __restrict__ W,
    const float* __restrict__ bias, unsigned short* __restrict__ C)
{
    __shared__ char sm[16384 + 24576];   // As [128][64], Bs [192][64]
    char* As = sm;
    char* Bs = sm + 16384;

    const int tid = threadIdx.x, lane = tid & 63, wid = tid >> 6;
    const int wr = wid >> 2, wcl = wid & 3;
    const int m0 = blockIdx.x * 128, n0 = blockIdx.y * 192;

    f32x4 acc[4][3];
    #pragma unroll
    for (int m = 0; m < 4; ++m)
        #pragma unroll
        for (int n = 0; n < 3; ++n) acc[m][n] = (f32x4)(0.f);

    for (int k0 = 0; k0 < 256; k0 += 64) {
        #pragma unroll
        for (int j = 0; j < 5; ++j) {
            const int i = j * 512 + tid;               // 0..2559
            if (i < 1024) {
                const int row = i >> 3, k8 = (i & 7) ^ (row & 7);
                gload16(A + (size_t)(m0 + row) * 256 + k0 + k8 * 8, As + i * 16);
            } else {
                const int ii = i - 1024;
                const int row = ii >> 3, k8 = (ii & 7) ^ (row & 7);
                gload16(W + (size_t)(n0 + row) * 256 + k0 + k8 * 8, Bs + ii * 16);
            }
        }
        __syncthreads();
        #pragma unroll
        for (int ks = 0; ks < 2; ++ks) {
            bf16x8 af[4], bfr[3];
            #pragma unroll
            for (int m = 0; m < 4; ++m) {
                const int row = wr * 64 + m * 16 + (lane & 15);
                const int off = (row * 128 + ks * 64 + (lane >> 4) * 16) ^ ((row & 7) << 4);
                af[m] = *(const bf16x8*)(As + off);
            }
            #pragma unroll
            for (int n = 0; n < 3; ++n) {
                const int row = wcl * 48 + n * 16 + (lane & 15);
                const int off = (row * 128 + ks * 64 + (lane >> 4) * 16) ^ ((row & 7) << 4);
                bfr[n] = *(const bf16x8*)(Bs + off);
            }
            #pragma unroll
            for (int m = 0; m < 4; ++m)
                #pragma unroll
                for (int n = 0; n < 3; ++n)
                    acc[m][n] = __builtin_amdgcn_mfma_f32_16x16x32_bf16(
                        af[m], bfr[n], acc[m][n], 0, 0, 0);
        }
        __syncthreads();
    }

    #pragma unroll
    for (int n = 0; n < 3; ++n) {
        const int c = n0 + wcl * 48 + n * 16 + (lane & 15);
        const float bv = bias[c];
        #pragma unroll
        for (int m = 0; m < 4; ++m) {
            const int rbase = m0 + wr * 64 + m * 16 + ((lane >> 4) << 2);
            #pragma unroll
            for (int j = 0; j < 4; ++j)
                C[(size_t)(rbase + j) * 768 + c] = f2bf(acc[m][n][j] + bv);
        }
    }
}

// ---------------------------------------------------------------------------
// Fused tail: attention -> out-proj + res + LN1 -> FFN1(relu) -> FFN2 + res
// + LN2 -> out. One block = 32 rows, 512 threads (8 waves). Intermediates
// (attn-out, x, hid) live entirely in LDS; weights streamed via gload16.
// LDS: smA [32][256] (attn-out, then x) | smB staging (<=64K) | smH [32][512].
// ---------------------------------------------------------------------------
__global__ __launch_bounds__(512) void tail_fused(
    const unsigned short* __restrict__ qkv, const unsigned short* __restrict__ Wo,
    const unsigned short* __restrict__ W1, const unsigned short* __restrict__ W2,
    const float* __restrict__ resf, const float* __restrict__ b_out,
    const float* __restrict__ g1, const float* __restrict__ be1,
    const float* __restrict__ b1, const float* __restrict__ b2,
    const float* __restrict__ g2, const float* __restrict__ be2,
    float* __restrict__ out)
{
    __shared__ __align__(16) char sm[116736];
    char* smA = sm;                      // [32][256] bf16, 16 KB
    char* smB = sm + 16384;              // staging, up to 64 KB
    char* smH = sm + 81920;              // [32][512] bf16, 32 KB
    float* part = (float*)(sm + 114688); // [8][32][2]

    const int tid = threadIdx.x, lane = tid & 63, wid = tid >> 6;
    const int m0 = blockIdx.x * 32;
    const int b = m0 >> 11, t0 = m0 & 2047;

    // ========== phase A: windowed attention (256 threads: 32 rows x 8 heads) ==========
    if (tid < 256) {
        const int h = tid & 7, tl = tid >> 3;
        const int t = t0 + tl;
        const unsigned short* base = qkv + (size_t)b * T_LEN * 768;

        float q[32];
        const unsigned short* qp = base + (size_t)t * 768 + h * 32;
        #pragma unroll
        for (int jj = 0; jj < 4; ++jj) {
            u16x8 u = *(const u16x8*)(qp + jj * 8);
            #pragma unroll
            for (int e = 0; e < 8; ++e) q[jj * 8 + e] = bf2f(u[e]);
        }
        const unsigned short* kbase = base + 256 + h * 32;
        const unsigned short* vbase = base + 512 + h * 32;

        float sc[9], mx = -1e30f;
        #pragma unroll
        for (int j = 0; j < 9; ++j) {
            const int kr0 = t - 4 + j;
            const int krm = min(max(kr0, 0), T_LEN - 1);
            const unsigned short* kr = kbase + (size_t)krm * 768;
            float d = 0.f;
            #pragma unroll
            for (int jj = 0; jj < 4; ++jj) {
                u16x8 u = *(const u16x8*)(kr + jj * 8);
                #pragma unroll
                for (int e = 0; e < 8; ++e) d += q[jj * 8 + e] * bf2f(u[e]);
            }
            sc[j] = (kr0 == krm) ? d * 0.17677669529663687f : -1e30f;
            mx = fmaxf(mx, sc[j]);
        }
        float sum = 0.f;
        #pragma unroll
        for (int j = 0; j < 9; ++j) { sc[j] = expf(sc[j] - mx); sum += sc[j]; }
        const float inv = 1.f / sum;

        float ov[32] = {};
        #pragma unroll
        for (int j = 0; j < 9; ++j) {
            const float p = sc[j] * inv;
            const int krm = min(max(t - 4 + j, 0), T_LEN - 1);
            const unsigned short* vr = vbase + (size_t)krm * 768;
            #pragma unroll
            for (int jj = 0; jj < 4; ++jj) {
                u16x8 u = *(const u16x8*)(vr + jj * 8);
                #pragma unroll
                for (int e = 0; e < 8; ++e) ov[jj * 8 + e] += p * bf2f(u[e]);
            }
        }
        #pragma unroll
        for (int jj = 0; jj < 4; ++jj) {
            u16x8 p8;
            #pragma unroll
            for (int e = 0; e < 8; ++e) p8[e] = f2bf(ov[jj * 8 + e]);
            const int off = tl * 512 + ((h * 4 + jj) ^ (tl & 7)) * 16;
            *(u16x8*)(smA + off) = p8;
        }
    }
    __syncthreads();

    // ========== phase B: out-proj (32x256 @ Wo[256,256]^T) ==========
    {
        f32x4 acc[2][2];
        #pragma unroll
        for (int m = 0; m < 2; ++m)
            #pragma unroll
            for (int n = 0; n < 2; ++n) acc[m][n] = (f32x4)(0.f);

        for (int k0 = 0; k0 < 256; k0 += 64) {
            #pragma unroll
            for (int j = 0; j < 4; ++j) {
                const int i = j * 512 + tid, row = i >> 3, k8 = (i & 7) ^ (row & 7);
                gload16(Wo + (size_t)row * 256 + k0 + k8 * 8, smB + i * 16);
            }
            __syncthreads();
            #pragma unroll
            for (int ks = 0; ks < 2; ++ks) {
                bf16x8 af[2], bfr[2];
                #pragma unroll
                for (int m = 0; m < 2; ++m) {
                    const int r = m * 16 + (lane & 15);
                    const int ch = (k0 >> 3) + ks * 4 + (lane >> 4);
                    af[m] = *(const bf16x8*)(smA + r * 512 + (ch ^ (r & 7)) * 16);
                }
                #pragma unroll
                for (int n = 0; n < 2; ++n) {
                    const int rB = wid * 32 + n * 16 + (lane & 15);
                    bfr[n] = *(const bf16x8*)(smB + rB * 128 + (((ks * 4 + (lane >> 4)) ^ (rB & 7)) * 16));
                }
                #pragma unroll
                for (int m = 0; m < 2; ++m)
                    #pragma unroll
                    for (int n = 0; n < 2; ++n)
                        acc[m][n] = __builtin_amdgcn_mfma_f32_16x16x32_bf16(
                            af[m], bfr[n], acc[m][n], 0, 0, 0);
            }
            __syncthreads();
        }

        // epilogue: + b_out + features, LN1, x -> smA (bf16, swizzled)
        float v[2][2][4], s[2][4], sq[2][4];
        #pragma unroll
        for (int m = 0; m < 2; ++m)
            #pragma unroll
            for (int j = 0; j < 4; ++j) { s[m][j] = 0.f; sq[m][j] = 0.f; }
        #pragma unroll
        for (int n = 0; n < 2; ++n) {
            const int c = wid * 32 + n * 16 + (lane & 15);
            const float bv = b_out[c];
            #pragma unroll
            for (int m = 0; m < 2; ++m) {
                const int rb = m * 16 + ((lane >> 4) << 2);
                #pragma unroll
                for (int j = 0; j < 4; ++j) {
                    float x = acc[m][n][j] + bv + resf[(size_t)(m0 + rb + j) * 256 + c];
                    v[m][n][j] = x; s[m][j] += x; sq[m][j] += x * x;
                }
            }
        }
        #pragma unroll
        for (int m = 0; m < 2; ++m)
            #pragma unroll
            for (int j = 0; j < 4; ++j) {
                #pragma unroll
                for (int msk = 1; msk <= 8; msk <<= 1) {
                    s[m][j]  += __shfl_xor(s[m][j], msk);
                    sq[m][j] += __shfl_xor(sq[m][j], msk);
                }
                if ((lane & 15) == 0) {
                    const int r = m * 16 + ((lane >> 4) << 2) + j;
                    part[(wid * 32 + r) * 2 + 0] = s[m][j];
                    part[(wid * 32 + r) * 2 + 1] = sq[m][j];
                }
            }
        __syncthreads();
        #pragma unroll
        for (int m = 0; m < 2; ++m) {
            const int rb = m * 16 + ((lane >> 4) << 2);
            #pragma unroll
            for (int j = 0; j < 4; ++j) {
                const int r = rb + j;
                float S = 0.f, SQ = 0.f;
                #pragma unroll
                for (int w = 0; w < 8; ++w) {
                    S += part[(w * 32 + r) * 2 + 0]; SQ += part[(w * 32 + r) * 2 + 1];
                }
                const float mean = S * (1.f / 256.f);
                const float var  = SQ * (1.f / 256.f) - mean * mean;
                const float rstd = rsqrtf(var + LN_EPS);
                #pragma unroll
                for (int n = 0; n < 2; ++n) {
                    const int c = wid * 32 + n * 16 + (lane & 15);
                    const float o = (v[m][n][j] - mean) * rstd * g1[c] + be1[c];
                    const int addr = r * 512 + (((c >> 3) ^ (r & 7)) << 4) + ((c & 7) << 1);
                    *(unsigned short*)(smA + addr) = f2bf(o);
                }
            }
        }
    }
    __syncthreads();

    // ========== phase C: FFN1 (32x512 = x @ W1[512,256]^T, relu) -> smH ==========
    {
        f32x4 acc[2][4];
        #pragma unroll
        for (int m = 0; m < 2; ++m)
            #pragma unroll
            for (int n = 0; n < 4; ++n) acc[m][n] = (f32x4)(0.f);

        for (int k0 = 0; k0 < 256; k0 += 64) {
            #pragma unroll
            for (int j = 0; j < 8; ++j) {
                const int i = j * 512 + tid, row = i >> 3, k8 = (i & 7) ^ (row & 7);
                gload16(W1 + (size_t)row * 256 + k0 + k8 * 8, smB + i * 16);
            }
            __syncthreads();
            #pragma unroll
            for (int ks = 0; ks < 2; ++ks) {
                bf16x8 af[2], bfr[4];
                #pragma unroll
                for (int m = 0; m < 2; ++m) {
                    const int r = m * 16 + (lane & 15);
                    const int ch = (k0 >> 3) + ks * 4 + (lane >> 4);
                    af[m] = *(const bf16x8*)(smA + r * 512 + (ch ^ (r & 7)) * 16);
                }
                #pragma unroll
                for (int n = 0; n < 4; ++n) {
                    const int rB = wid * 64 + n * 16 + (lane & 15);
                    bfr[n] = *(const bf16x8*)(smB + rB * 128 + (((ks * 4 + (lane >> 4)) ^ (rB & 7)) * 16));
                }
                #pragma unroll
                for (int m = 0; m < 2; ++m)
                    #pragma unroll
                    for (int n = 0; n < 4; ++n)
                        acc[m][n] = __builtin_amdgcn_mfma_f32_16x16x32_bf16(
                            af[m], bfr[n], acc[m][n], 0, 0, 0);
            }
            __syncthreads();
        }
        // hid = relu(acc + b1) -> smH (bf16, swizzled scalar writes)
        #pragma unroll
        for (int n = 0; n < 4; ++n) {
            const int c = wid * 64 + n * 16 + (lane & 15);
            const float bv = b1[c];
            #pragma unroll
            for (int m = 0; m < 2; ++m) {
                const int rb = m * 16 + ((lane >> 4) << 2);
                #pragma unroll
                for (int j = 0; j < 4; ++j) {
                    const int r = rb + j;
                    const int addr = r * 1024 + (((c >> 3) ^ (r & 7)) << 4) + ((c & 7) << 1);
                    *(unsigned short*)(smH + addr) = f2bf(fmaxf(acc[m][n][j] + bv, 0.f));
                }
            }
        }
    }
    __syncthreads();

    // ========== phase D: FFN2 (32x256 = hid @ W2[256,512]^T) + res + LN2 ==========
    {
        f32x4 acc[2][2];
        #pragma unroll
        for (int m = 0; m < 2; ++m)
            #pragma unroll
            for (int n = 0; n < 2; ++n) acc[m][n] = (f32x4)(0.f);

        for (int k0 = 0; k0 < 512; k0 += 64) {
            #pragma unroll
            for (int j = 0; j < 4; ++j) {
                const int i = j * 512 + tid, row = i >> 3, k8 = (i & 7) ^ (row & 7);
                gload16(W2 + (size_t)row * 512 + k0 + k8 * 8, smB + i * 16);
            }
            __syncthreads();
            #pragma unroll
            for (int ks = 0; ks < 2; ++ks) {
                bf16x8 af[2], bfr[2];
                #pragma unroll
                for (int m = 0; m < 2; ++m) {
                    const int r = m * 16 + (lane & 15);
                    const int ch = (k0 >> 3) + ks * 4 + (lane >> 4);
                    af[m] = *(const bf16x8*)(smH + r * 1024 + (ch ^ (r & 7)) * 16);
                }
                #pragma unroll
                for (int n = 0; n < 2; ++n) {
                    const int rB = wid * 32 + n * 16 + (lane & 15);
                    bfr[n] = *(const bf16x8*)(smB + rB * 128 + (((ks * 4 + (lane >> 4)) ^ (rB & 7)) * 16));
                }
                #pragma unroll
                for (int m = 0; m < 2; ++m)
                    #pragma unroll
                    for (int n = 0; n < 2; ++n)
                        acc[m][n] = __builtin_amdgcn_mfma_f32_16x16x32_bf16(
                            af[m], bfr[n], acc[m][n], 0, 0, 0);
            }
            __syncthreads();
        }

        // epilogue: + b2 + x(smA), LN2 -> out (f32)
        float v[2][2][4], s[2][4], sq[2][4];
        #pragma unroll
        for (int m = 0; m < 2; ++m)
            #pragma unroll
            for (int j = 0; j < 4; ++j) { s[m][j] = 0.f; sq[m][j] = 0.f; }
        #pragma unroll
        for (int n = 0; n < 2; ++n) {
            const int c = wid * 32 + n * 16 + (lane & 15);
            const float bv = b2[c];
            #pragma unroll
            for (int m = 0; m < 2; ++m) {
                const int rb = m * 16 + ((lane >> 4) << 2);
                #pragma unroll
                for (int j = 0; j < 4; ++j) {
                    const int r = rb + j;
                    const int addr = r * 512 + (((c >> 3) ^ (r & 7)) << 4) + ((c & 7) << 1);
                    float x = acc[m][n][j] + bv + bf2f(*(const unsigned short*)(smA + addr));
                    v[m][n][j] = x; s[m][j] += x; sq[m][j] += x * x;
                }
            }
        }
        #pragma unroll
        for (int m = 0; m < 2; ++m)
            #pragma unroll
            for (int j = 0; j < 4; ++j) {
                #pragma unroll
                for (int msk = 1; msk <= 8; msk <<= 1) {
                    s[m][j]  += __shfl_xor(s[m][j], msk);
                    sq[m][j] += __shfl_xor(sq[m][j], msk);
                }
                if ((lane & 15) == 0) {
                    const int r = m * 16 + ((lane >> 4) << 2) + j;
                    part[(wid * 32 + r) * 2 + 0] = s[m][j];
                    part[(wid * 32 + r) * 2 + 1] = sq[m][j];
                }
            }
        __syncthreads();
        #pragma unroll
        for (int m = 0; m < 2; ++m) {
            const int rb = m * 16 + ((lane >> 4) << 2);
            #pragma unroll
            for (int j = 0; j < 4; ++j) {
                const int r = rb + j;
                float S = 0.f, SQ = 0.f;
                #pragma unroll
                for (int w = 0; w < 8; ++w) {
                    S += part[(w * 32 + r) * 2 + 0]; SQ += part[(w * 32 + r) * 2 + 1];
                }
                const float mean = S * (1.f / 256.f);
                const float var  = SQ * (1.f / 256.f) - mean * mean;
                const float rstd = rsqrtf(var + LN_EPS);
                #pragma unroll
                for (int n = 0; n < 2; ++n) {
                    const int c = wid * 32 + n * 16 + (lane & 15);
                    const float o = (v[m][n][j] - mean) * rstd * g2[c] + be2[c];
                    out[(size_t)(m0 + r) * 256 + c] = o;
                }
            }
        }
    }
}

// ---------------------------------------------------------------------------
extern "C" void kernel_launch(void* const* d_in, const int* in_sizes, int n_in,
                              void* d_out, int out_size, void* d_ws, size_t ws_size,
                              hipStream_t stream) {
    const float* features = (const float*)d_in[0];
    const float* w_qkv    = (const float*)d_in[1];
    const float* b_qkv    = (const float*)d_in[2];
    const float* w_out    = (const float*)d_in[3];
    const float* b_out    = (const float*)d_in[4];
    const float* w1       = (const float*)d_in[5];
    const float* b1       = (const float*)d_in[6];
    const float* w2       = (const float*)d_in[7];
    const float* b2       = (const float*)d_in[8];
    const float* g1       = (const float*)d_in[9];
    const float* be1      = (const float*)d_in[10];
    const float* g2       = (const float*)d_in[11];
    const float* be2      = (const float*)d_in[12];
    // d_in[13] (mask) structurally determined by WIN=9 -> not read.

    unsigned short* wsu = (unsigned short*)d_ws;
    unsigned short* featbf = wsu;               // 2,097,152
    unsigned short* wqkvbf = wsu + 2097152;     //   196,608
    unsigned short* woutbf = wsu + 2293760;     //    65,536
    unsigned short* w1bf   = wsu + 2359296;     //   131,072
    unsigned short* w2bf   = wsu + 2490368;     //   131,072
    unsigned short* qkvbf  = wsu + 2621440;     // [8192][768]

    // 1) convert weights + features to bf16
    to_bf16_multi<<<1280, 256, 0, stream>>>(features, w_qkv, w_out, w1, w2, wsu);
    // 2) QKV projection
    qkv_gemm<<<dim3(64, 4), 512, 0, stream>>>(featbf, wqkvbf, b_qkv, qkvbf);
    // 3) fused tail: attn -> out-proj+LN1 -> FFN1 -> FFN2+LN2 -> out
    tail_fused<<<M_ROWS / 32, 512, 0, stream>>>(
        qkvbf, woutbf, w1bf, w2bf, features, b_out, g1, be1, b1, b2, g2, be2,
        (float*)d_out);
}

// Round 7
// 49.286 us; speedup vs baseline: 3.8760x; 1.0088x over previous
//
#include <hip/hip_runtime.h>
#include <math.h>

#define T_LEN 2048
#define LN_EPS 1e-5f
#define M_ROWS 8192

using u16x8  = __attribute__((ext_vector_type(8))) unsigned short;
using bf16x8 = __attribute__((ext_vector_type(8))) short;
using f32x4  = __attribute__((ext_vector_type(4))) float;

__device__ __forceinline__ unsigned short f2bf(float f) {
    unsigned int u = __float_as_uint(f);
    u += 0x7FFFu + ((u >> 16) & 1u);
    return (unsigned short)(u >> 16);
}
__device__ __forceinline__ float bf2f(unsigned short u) {
    return __uint_as_float(((unsigned int)u) << 16);
}
__device__ __forceinline__ void gload16(const void* g, void* l) {
    __builtin_amdgcn_global_load_lds(
        (const __attribute__((address_space(1))) unsigned int*)g,
        (__attribute__((address_space(3))) unsigned int*)l, 16, 0, 0);
}

// ---------------------------------------------------------------------------
// fp32 -> bf16 weights only: {w_qkv, w_out, w1, w2} = 524288 elems.
// ---------------------------------------------------------------------------
__global__ __launch_bounds__(256) void conv_w(
    const float* __restrict__ s1, const float* __restrict__ s2,
    const float* __restrict__ s3, const float* __restrict__ s4,
    unsigned short* __restrict__ dst)
{
    const int i8 = (blockIdx.x * 256 + threadIdx.x) * 8;
    const float* src; int off;
    if (i8 < 196608)      { src = s1; off = 0; }
    else if (i8 < 262144) { src = s2; off = 196608; }
    else if (i8 < 393216) { src = s3; off = 262144; }
    else                  { src = s4; off = 393216; }
    const float4 a = *(const float4*)(src + (i8 - off));
    const float4 c = *(const float4*)(src + (i8 - off) + 4);
    u16x8 p;
    p[0] = f2bf(a.x); p[1] = f2bf(a.y); p[2] = f2bf(a.z); p[3] = f2bf(a.w);
    p[4] = f2bf(c.x); p[5] = f2bf(c.y); p[6] = f2bf(c.z); p[7] = f2bf(c.w);
    *(u16x8*)(dst + i8) = p;
}

// ---------------------------------------------------------------------------
// mega32: one block = 32 output rows. Phases (all block-local, LDS-resident):
//  P0 convert features rows [t0-4, t0+43] -> smF[48][256] bf16 (swizzled)
//  P1 qkv = smF @ Wqkv^T (48x768) -> smQ[48][776]
//  P2 windowed attention (LDS-only reads) -> smA[32][256]
//  P3 out-proj + bias + res(features) + LN1 -> x in smA
//  P4 FFN1 (relu) -> smH[32][512] (aliases smQ)
//  P5 FFN2 + bias + res(x) + LN2 -> out (f32)
// Weights streamed via swizzled-source global_load_lds into smB[256][64].
// ---------------------------------------------------------------------------
__global__ __launch_bounds__(512) void mega32(
    const float* __restrict__ features,
    const unsigned short* __restrict__ Wqkv, const float* __restrict__ b_qkv,
    const unsigned short* __restrict__ Wo, const float* __restrict__ b_out,
    const unsigned short* __restrict__ W1, const float* __restrict__ b1,
    const unsigned short* __restrict__ W2, const float* __restrict__ b2,
    const float* __restrict__ g1, const float* __restrict__ be1,
    const float* __restrict__ g2, const float* __restrict__ be2,
    float* __restrict__ out)
{
    __shared__ __align__(16) char sm[133888];
    char* smA = sm;                       // 24576 B: smF[48][256] / attn-out,x [32][256]
    char* smB = sm + 24576;               // 32768 B: weight staging [256][64]
    char* smQ = sm + 57344;               // 74496 B: qkv [48][776] bf16; later smH[32][512]
    char* smH = smQ;
    float* part = (float*)(sm + 131840);  // [8][32][2]

    const int tid = threadIdx.x, lane = tid & 63, wid = tid >> 6;
    const int m0 = blockIdx.x * 32;
    const int b = m0 >> 11, t0 = m0 & 2047;

    // ================= P0: features -> smF bf16 (swizzled) =================
    #pragma unroll
    for (int j = 0; j < 3; ++j) {
        const int i = j * 512 + tid;          // 1536 chunks of 16 B
        const int e = i >> 5, ch = i & 31;
        const int gt = min(max(t0 - 4 + e, 0), T_LEN - 1);
        const float* src = features + ((size_t)(b * T_LEN + gt)) * 256 + ch * 8;
        const float4 a = *(const float4*)src;
        const float4 c = *(const float4*)(src + 4);
        u16x8 p;
        p[0] = f2bf(a.x); p[1] = f2bf(a.y); p[2] = f2bf(a.z); p[3] = f2bf(a.w);
        p[4] = f2bf(c.x); p[5] = f2bf(c.y); p[6] = f2bf(c.z); p[7] = f2bf(c.w);
        *(u16x8*)(smA + e * 512 + ((ch ^ (e & 7)) << 4)) = p;
    }
    __syncthreads();

    // ================= P1: qkv GEMM 48x768, 3 N-chunks of 256 =================
    for (int nc = 0; nc < 3; ++nc) {
        f32x4 acc[3][2];
        #pragma unroll
        for (int m = 0; m < 3; ++m)
            #pragma unroll
            for (int n = 0; n < 2; ++n) acc[m][n] = (f32x4)(0.f);

        for (int k0 = 0; k0 < 256; k0 += 64) {
            #pragma unroll
            for (int j = 0; j < 4; ++j) {
                const int i = j * 512 + tid;
                const int row = i >> 3, k8 = (i & 7) ^ (row & 7);
                gload16(Wqkv + (size_t)(nc * 256 + row) * 256 + k0 + k8 * 8, smB + i * 16);
            }
            __syncthreads();
            #pragma unroll
            for (int ks = 0; ks < 2; ++ks) {
                bf16x8 af[3], bfr[2];
                #pragma unroll
                for (int m = 0; m < 3; ++m) {
                    const int r = m * 16 + (lane & 15);
                    const int ch = (k0 >> 3) + ks * 4 + (lane >> 4);
                    af[m] = *(const bf16x8*)(smA + r * 512 + ((ch ^ (r & 7)) << 4));
                }
                #pragma unroll
                for (int n = 0; n < 2; ++n) {
                    const int rB = wid * 32 + n * 16 + (lane & 15);
                    bfr[n] = *(const bf16x8*)(smB + rB * 128 + (((ks * 4 + (lane >> 4)) ^ (rB & 7)) << 4));
                }
                #pragma unroll
                for (int m = 0; m < 3; ++m)
                    #pragma unroll
                    for (int n = 0; n < 2; ++n)
                        acc[m][n] = __builtin_amdgcn_mfma_f32_16x16x32_bf16(
                            af[m], bfr[n], acc[m][n], 0, 0, 0);
            }
            __syncthreads();
        }
        // epilogue -> smQ[48][776]
        #pragma unroll
        for (int n = 0; n < 2; ++n) {
            const int cl = wid * 32 + n * 16 + (lane & 15);
            const float bv = b_qkv[nc * 256 + cl];
            #pragma unroll
            for (int m = 0; m < 3; ++m) {
                const int rb = m * 16 + ((lane >> 4) << 2);
                #pragma unroll
                for (int j = 0; j < 4; ++j)
                    *(unsigned short*)(smQ + ((size_t)(rb + j) * 776 + nc * 256 + cl) * 2) =
                        f2bf(acc[m][n][j] + bv);
            }
        }
    }
    __syncthreads();

    // ================= P2: windowed attention (LDS reads) =================
    if (tid < 256) {
        const int h = tid & 7, tl = tid >> 3;

        float q[32];
        #pragma unroll
        for (int jj = 0; jj < 4; ++jj) {
            u16x8 u = *(const u16x8*)(smQ + ((tl + 4) * 776 + h * 32 + jj * 8) * 2);
            #pragma unroll
            for (int e = 0; e < 8; ++e) q[jj * 8 + e] = bf2f(u[e]);
        }

        float sc[9], mx = -1e30f;
        #pragma unroll
        for (int j = 0; j < 9; ++j) {
            const int kr0 = t0 + tl - 4 + j;
            const bool valid = (kr0 >= 0) && (kr0 < T_LEN);
            const char* kr = smQ + ((tl + j) * 776 + 256 + h * 32) * 2;
            float d = 0.f;
            #pragma unroll
            for (int jj = 0; jj < 4; ++jj) {
                u16x8 u = *(const u16x8*)(kr + jj * 16);
                #pragma unroll
                for (int e = 0; e < 8; ++e) d += q[jj * 8 + e] * bf2f(u[e]);
            }
            sc[j] = valid ? d * 0.17677669529663687f : -1e30f;
            mx = fmaxf(mx, sc[j]);
        }
        float sum = 0.f;
        #pragma unroll
        for (int j = 0; j < 9; ++j) { sc[j] = expf(sc[j] - mx); sum += sc[j]; }
        const float inv = 1.f / sum;

        float ov[32] = {};
        #pragma unroll
        for (int j = 0; j < 9; ++j) {
            const float p = sc[j] * inv;
            const char* vr = smQ + ((tl + j) * 776 + 512 + h * 32) * 2;
            #pragma unroll
            for (int jj = 0; jj < 4; ++jj) {
                u16x8 u = *(const u16x8*)(vr + jj * 16);
                #pragma unroll
                for (int e = 0; e < 8; ++e) ov[jj * 8 + e] += p * bf2f(u[e]);
            }
        }
        #pragma unroll
        for (int jj = 0; jj < 4; ++jj) {
            u16x8 p8;
            #pragma unroll
            for (int e = 0; e < 8; ++e) p8[e] = f2bf(ov[jj * 8 + e]);
            const int off = tl * 512 + ((h * 4 + jj) ^ (tl & 7)) * 16;
            *(u16x8*)(smA + off) = p8;
        }
    }
    // no barrier needed here: P3's first stage->barrier orders smA reads

    // ================= P3: out-proj 32x256 + res + LN1 -> x in smA =================
    {
        f32x4 acc[2][2];
        #pragma unroll
        for (int m = 0; m < 2; ++m)
            #pragma unroll
            for (int n = 0; n < 2; ++n) acc[m][n] = (f32x4)(0.f);

        for (int k0 = 0; k0 < 256; k0 += 64) {
            #pragma unroll
            for (int j = 0; j < 4; ++j) {
                const int i = j * 512 + tid;
                const int row = i >> 3, k8 = (i & 7) ^ (row & 7);
                gload16(Wo + (size_t)row * 256 + k0 + k8 * 8, smB + i * 16);
            }
            __syncthreads();
            #pragma unroll
            for (int ks = 0; ks < 2; ++ks) {
                bf16x8 af[2], bfr[2];
                #pragma unroll
                for (int m = 0; m < 2; ++m) {
                    const int r = m * 16 + (lane & 15);
                    const int ch = (k0 >> 3) + ks * 4 + (lane >> 4);
                    af[m] = *(const bf16x8*)(smA + r * 512 + ((ch ^ (r & 7)) << 4));
                }
                #pragma unroll
                for (int n = 0; n < 2; ++n) {
                    const int rB = wid * 32 + n * 16 + (lane & 15);
                    bfr[n] = *(const bf16x8*)(smB + rB * 128 + (((ks * 4 + (lane >> 4)) ^ (rB & 7)) << 4));
                }
                #pragma unroll
                for (int m = 0; m < 2; ++m)
                    #pragma unroll
                    for (int n = 0; n < 2; ++n)
                        acc[m][n] = __builtin_amdgcn_mfma_f32_16x16x32_bf16(
                            af[m], bfr[n], acc[m][n], 0, 0, 0);
            }
            __syncthreads();
        }

        // epilogue: + b_out + features, LN1 -> smA (bf16, swizzled)
        float v[2][2][4], s[2][4], sq[2][4];
        #pragma unroll
        for (int m = 0; m < 2; ++m)
            #pragma unroll
            for (int j = 0; j < 4; ++j) { s[m][j] = 0.f; sq[m][j] = 0.f; }
        #pragma unroll
        for (int n = 0; n < 2; ++n) {
            const int c = wid * 32 + n * 16 + (lane & 15);
            const float bv = b_out[c];
            #pragma unroll
            for (int m = 0; m < 2; ++m) {
                const int rb = m * 16 + ((lane >> 4) << 2);
                #pragma unroll
                for (int j = 0; j < 4; ++j) {
                    float x = acc[m][n][j] + bv + features[(size_t)(m0 + rb + j) * 256 + c];
                    v[m][n][j] = x; s[m][j] += x; sq[m][j] += x * x;
                }
            }
        }
        #pragma unroll
        for (int m = 0; m < 2; ++m)
            #pragma unroll
            for (int j = 0; j < 4; ++j) {
                #pragma unroll
                for (int msk = 1; msk <= 8; msk <<= 1) {
                    s[m][j]  += __shfl_xor(s[m][j], msk);
                    sq[m][j] += __shfl_xor(sq[m][j], msk);
                }
                if ((lane & 15) == 0) {
                    const int r = m * 16 + ((lane >> 4) << 2) + j;
                    part[(wid * 32 + r) * 2 + 0] = s[m][j];
                    part[(wid * 32 + r) * 2 + 1] = sq[m][j];
                }
            }
        __syncthreads();
        #pragma unroll
        for (int m = 0; m < 2; ++m) {
            const int rb = m * 16 + ((lane >> 4) << 2);
            #pragma unroll
            for (int j = 0; j < 4; ++j) {
                const int r = rb + j;
                float S = 0.f, SQ = 0.f;
                #pragma unroll
                for (int w = 0; w < 8; ++w) {
                    S += part[(w * 32 + r) * 2 + 0]; SQ += part[(w * 32 + r) * 2 + 1];
                }
                const float mean = S * (1.f / 256.f);
                const float var  = SQ * (1.f / 256.f) - mean * mean;
                const float rstd = rsqrtf(var + LN_EPS);
                #pragma unroll
                for (int n = 0; n < 2; ++n) {
                    const int c = wid * 32 + n * 16 + (lane & 15);
                    const float o = (v[m][n][j] - mean) * rstd * g1[c] + be1[c];
                    const int addr = r * 512 + (((c >> 3) ^ (r & 7)) << 4) + ((c & 7) << 1);
                    *(unsigned short*)(smA + addr) = f2bf(o);
                }
            }
        }
    }
    __syncthreads();

    // ================= P4: FFN1 32x512 (relu) -> smH, two 256-col halves =================
    for (int nh = 0; nh < 2; ++nh) {
        f32x4 acc[2][2];
        #pragma unroll
        for (int m = 0; m < 2; ++m)
            #pragma unroll
            for (int n = 0; n < 2; ++n) acc[m][n] = (f32x4)(0.f);

        for (int k0 = 0; k0 < 256; k0 += 64) {
            #pragma unroll
            for (int j = 0; j < 4; ++j) {
                const int i = j * 512 + tid;
                const int row = i >> 3, k8 = (i & 7) ^ (row & 7);
                gload16(W1 + (size_t)(nh * 256 + row) * 256 + k0 + k8 * 8, smB + i * 16);
            }
            __syncthreads();
            #pragma unroll
            for (int ks = 0; ks < 2; ++ks) {
                bf16x8 af[2], bfr[2];
                #pragma unroll
                for (int m = 0; m < 2; ++m) {
                    const int r = m * 16 + (lane & 15);
                    const int ch = (k0 >> 3) + ks * 4 + (lane >> 4);
                    af[m] = *(const bf16x8*)(smA + r * 512 + ((ch ^ (r & 7)) << 4));
                }
                #pragma unroll
                for (int n = 0; n < 2; ++n) {
                    const int rB = wid * 32 + n * 16 + (lane & 15);
                    bfr[n] = *(const bf16x8*)(smB + rB * 128 + (((ks * 4 + (lane >> 4)) ^ (rB & 7)) << 4));
                }
                #pragma unroll
                for (int m = 0; m < 2; ++m)
                    #pragma unroll
                    for (int n = 0; n < 2; ++n)
                        acc[m][n] = __builtin_amdgcn_mfma_f32_16x16x32_bf16(
                            af[m], bfr[n], acc[m][n], 0, 0, 0);
            }
            __syncthreads();
        }
        // epilogue: relu(acc + b1) -> smH[32][512] (swizzled)
        #pragma unroll
        for (int n = 0; n < 2; ++n) {
            const int c = nh * 256 + wid * 32 + n * 16 + (lane & 15);
            const float bv = b1[c];
            #pragma unroll
            for (int m = 0; m < 2; ++m) {
                const int rb = m * 16 + ((lane >> 4) << 2);
                #pragma unroll
                for (int j = 0; j < 4; ++j) {
                    const int r = rb + j;
                    const int addr = r * 1024 + (((c >> 3) ^ (r & 7)) << 4) + ((c & 7) << 1);
                    *(unsigned short*)(smH + addr) = f2bf(fmaxf(acc[m][n][j] + bv, 0.f));
                }
            }
        }
    }
    __syncthreads();

    // ================= P5: FFN2 32x256 + res(x) + LN2 -> out =================
    {
        f32x4 acc[2][2];
        #pragma unroll
        for (int m = 0; m < 2; ++m)
            #pragma unroll
            for (int n = 0; n < 2; ++n) acc[m][n] = (f32x4)(0.f);

        for (int k0 = 0; k0 < 512; k0 += 64) {
            #pragma unroll
            for (int j = 0; j < 4; ++j) {
                const int i = j * 512 + tid;
                const int row = i >> 3, k8 = (i & 7) ^ (row & 7);
                gload16(W2 + (size_t)row * 512 + k0 + k8 * 8, smB + i * 16);
            }
            __syncthreads();
            #pragma unroll
            for (int ks = 0; ks < 2; ++ks) {
                bf16x8 af[2], bfr[2];
                #pragma unroll
                for (int m = 0; m < 2; ++m) {
                    const int r = m * 16 + (lane & 15);
                    const int ch = (k0 >> 3) + ks * 4 + (lane >> 4);
                    af[m] = *(const bf16x8*)(smH + r * 1024 + ((ch ^ (r & 7)) << 4));
                }
                #pragma unroll
                for (int n = 0; n < 2; ++n) {
                    const int rB = wid * 32 + n * 16 + (lane & 15);
                    bfr[n] = *(const bf16x8*)(smB + rB * 128 + (((ks * 4 + (lane >> 4)) ^ (rB & 7)) << 4));
                }
                #pragma unroll
                for (int m = 0; m < 2; ++m)
                    #pragma unroll
                    for (int n = 0; n < 2; ++n)
                        acc[m][n] = __builtin_amdgcn_mfma_f32_16x16x32_bf16(
                            af[m], bfr[n], acc[m][n], 0, 0, 0);
            }
            __syncthreads();
        }

        // epilogue: + b2 + x(smA), LN2 -> out (f32)
        float v[2][2][4], s[2][4], sq[2][4];
        #pragma unroll
        for (int m = 0; m < 2; ++m)
            #pragma unroll
            for (int j = 0; j < 4; ++j) { s[m][j] = 0.f; sq[m][j] = 0.f; }
        #pragma unroll
        for (int n = 0; n < 2; ++n) {
            const int c = wid * 32 + n * 16 + (lane & 15);
            const float bv = b2[c];
            #pragma unroll
            for (int m = 0; m < 2; ++m) {
                const int rb = m * 16 + ((lane >> 4) << 2);
                #pragma unroll
                for (int j = 0; j < 4; ++j) {
                    const int r = rb + j;
                    const int addr = r * 512 + (((c >> 3) ^ (r & 7)) << 4) + ((c & 7) << 1);
                    float x = acc[m][n][j] + bv + bf2f(*(const unsigned short*)(smA + addr));
                    v[m][n][j] = x; s[m][j] += x; sq[m][j] += x * x;
                }
            }
        }
        #pragma unroll
        for (int m = 0; m < 2; ++m)
            #pragma unroll
            for (int j = 0; j < 4; ++j) {
                #pragma unroll
                for (int msk = 1; msk <= 8; msk <<= 1) {
                    s[m][j]  += __shfl_xor(s[m][j], msk);
                    sq[m][j] += __shfl_xor(sq[m][j], msk);
                }
                if ((lane & 15) == 0) {
                    const int r = m * 16 + ((lane >> 4) << 2) + j;
                    part[(wid * 32 + r) * 2 + 0] = s[m][j];
                    part[(wid * 32 + r) * 2 + 1] = sq[m][j];
                }
            }
        __syncthreads();
        #pragma unroll
        for (int m = 0; m < 2; ++m) {
            const int rb = m * 16 + ((lane >> 4) << 2);
            #pragma unroll
            for (int j = 0; j < 4; ++j) {
                const int r = rb + j;
                float S = 0.f, SQ = 0.f;
                #pragma unroll
                for (int w = 0; w < 8; ++w) {
                    S += part[(w * 32 + r) * 2 + 0]; SQ += part[(w * 32 + r) * 2 + 1];
                }
                const float mean = S * (1.f / 256.f);
                const float var  = SQ * (1.f / 256.f) - mean * mean;
                const float rstd = rsqrtf(var + LN_EPS);
                #pragma unroll
                for (int n = 0; n < 2; ++n) {
                    const int c = wid * 32 + n * 16 + (lane & 15);
                    const float o = (v[m][n][j] - mean) * rstd * g2[c] + be2[c];
                    out[(size_t)(m0 + r) * 256 + c] = o;
                }
            }
        }
    }
}

// ---------------------------------------------------------------------------
extern "C" void kernel_launch(void* const* d_in, const int* in_sizes, int n_in,
                              void* d_out, int out_size, void* d_ws, size_t ws_size,
                              hipStream_t stream) {
    const float* features = (const float*)d_in[0];
    const float* w_qkv    = (const float*)d_in[1];
    const float* b_qkv    = (const float*)d_in[2];
    const float* w_out    = (const float*)d_in[3];
    const float* b_out    = (const float*)d_in[4];
    const float* w1       = (const float*)d_in[5];
    const float* b1       = (const float*)d_in[6];
    const float* w2       = (const float*)d_in[7];
    const float* b2       = (const float*)d_in[8];
    const float* g1       = (const float*)d_in[9];
    const float* be1      = (const float*)d_in[10];
    const float* g2       = (const float*)d_in[11];
    const float* be2      = (const float*)d_in[12];
    // d_in[13] (mask) structurally determined by WIN=9 -> not read.

    unsigned short* wsu = (unsigned short*)d_ws;
    unsigned short* wqkvbf = wsu;               // 196,608
    unsigned short* woutbf = wsu + 196608;      //  65,536
    unsigned short* w1bf   = wsu + 262144;      // 131,072
    unsigned short* w2bf   = wsu + 393216;      // 131,072

    // 1) convert weights to bf16 (1 MB total)
    conv_w<<<256, 256, 0, stream>>>(w_qkv, w_out, w1, w2, wsu);
    // 2) fully fused encoder
    mega32<<<M_ROWS / 32, 512, 0, stream>>>(
        features, wqkvbf, b_qkv, woutbf, b_out, w1bf, b1, w2bf, b2,
        g1, be1, g2, be2, (float*)d_out);
}